// Round 20
// baseline (291.857 us; speedup 1.0000x reference)
//
#include <hip/hip_runtime.h>
#include <cstdint>

#define DEVFN __device__ __forceinline__

typedef __bf16 bf16x8 __attribute__((ext_vector_type(8)));
typedef float f32x4 __attribute__((ext_vector_type(4)));
typedef unsigned int uint;

constexpr int Bc = 8, Sc = 2048, Ec = 512, Hc = 8, HDc = 64, NI = 64;
constexpr int Mtot = Bc * Sc;  // 16384
constexpr int Kdim = Ec;       // 512
constexpr int MAXITEMS = 128;
constexpr int NBLK = 512;      // persistent grid: 256 CUs x 2 blocks (64KB LDS each)

DEVFN unsigned short f2bf(float f) {
  unsigned u = __builtin_bit_cast(unsigned, f);
  u += 0x7fffu + ((u >> 16) & 1u);  // RNE (inputs finite)
  return (unsigned short)(u >> 16);
}

typedef const void __attribute__((address_space(1))) gvoid_t;
typedef void __attribute__((address_space(3))) lvoid_t;
DEVFN void gload16(const void* g, void* l) {
  __builtin_amdgcn_global_load_lds((gvoid_t*)g, (lvoid_t*)l, 16, 0, 0);
}

DEVFN uint cvtpk(float lo, float hi) {
  uint r;
  asm("v_cvt_pk_bf16_f32 %0, %1, %2" : "=v"(r) : "v"(lo), "v"(hi));
  return r;
}

#define WAIT_VM_BARRIER(N)                                            \
  do {                                                                \
    asm volatile("s_waitcnt vmcnt(" #N ")\n\ts_barrier" ::: "memory"); \
    __builtin_amdgcn_sched_barrier(0);                                \
  } while (0)
#define WAIT_LGKM_BARRIER()                                            \
  do {                                                                 \
    asm volatile("s_waitcnt lgkmcnt(0)\n\ts_barrier" ::: "memory");    \
    __builtin_amdgcn_sched_barrier(0);                                 \
  } while (0)

// Device-scope grid barrier for co-resident persistent blocks.
// Round-20 fix: exponential-backoff polling. Round 19's tight s_sleep(2) spin
// produced ~8200 same-address atomics/us from 512 pollers; the serialized L2
// atomic unit queued arrivals behind polls -> tens of us per barrier. Backoff
// cuts poll pressure ~60x; worst-case added latency ~3us/barrier.
DEVFN void grid_bar(int* cnt) {
  __syncthreads();
  if (threadIdx.x == 0) {
    __threadfence();           // release: my phase's stores visible
    atomicAdd(cnt, 1);
    int it = 0;
    while (atomicAdd(cnt, 0) < NBLK) {
      if (it < 2) {
        // fast path: immediate re-poll for nearly-synchronized barriers
      } else if (it < 4) {
        __builtin_amdgcn_s_sleep(8);
      } else if (it < 8) {
        __builtin_amdgcn_s_sleep(32);
      } else {
        __builtin_amdgcn_s_sleep(127);
      }
      ++it;
    }
    __threadfence();           // acquire
  }
  __syncthreads();
}

__global__ __launch_bounds__(256, 2) void mega_kernel(
    const int* __restrict__ ids, const float* __restrict__ x,
    const float* __restrict__ Wq, const float* __restrict__ Wk,
    const float* __restrict__ Wv, const float* __restrict__ Wo,
    const float* __restrict__ bq, const float* __restrict__ bk,
    const float* __restrict__ bv, const float* __restrict__ bo,
    ushort* __restrict__ xb, ushort* __restrict__ Wcat, ushort* __restrict__ Wob,
    ushort* __restrict__ qkv, ushort* __restrict__ obuf,
    int* __restrict__ perm, int* __restrict__ gstart, int* __restrict__ gsz,
    int* __restrict__ items, int* __restrict__ nitems,
    float* __restrict__ out, int* __restrict__ bars) {
  __shared__ __align__(16) char ldsraw[65536];
  const int tid = threadIdx.x;
  const int lane = tid & 63;
  const int wave = tid >> 6;

  // ================= phase 0: sort (block 0) + cvt_w/cvt_x (blocks 1..511) ======
  if (blockIdx.x == 0) {
    int* sid = (int*)ldsraw;            // [Sc]
    int* hist = sid + Sc;               // [NI]
    int* base = hist + NI;              // [NI]
    int t = tid;
    if (t < NI) hist[t] = 0;
    for (int i = t; i < Sc; i += 256) sid[i] = ids[i];
    __syncthreads();
    for (int i = t; i < Sc; i += 256) atomicAdd(&hist[sid[i]], 1);
    __syncthreads();
    if (t == 0) {
      int run = 0;
      for (int g = 0; g < NI; ++g) { base[g] = run; run += hist[g]; }
      int cnt = 0;
      for (int g = 0; g < NI; ++g)
        for (int q0 = 0; q0 < hist[g]; q0 += 32) items[cnt++] = (g << 16) | q0;
      *nitems = cnt;
    }
    __syncthreads();
    if (t < NI) { gstart[t] = base[t]; gsz[t] = hist[t]; }
    int w = t >> 6;
    for (int g = w; g < NI; g += 4) {
      int run = base[g];
      for (int c = 0; c < Sc; c += 64) {
        int tok = c + lane;
        int id = sid[tok];
        unsigned long long mask = __ballot(id == g);
        if (id == g) {
          int rank = __popcll(mask & ((1ull << lane) - 1ull));
          perm[run + rank] = tok;
        }
        run += __popcll(mask);
      }
    }
  } else {
    // 9216 conversion units (1024 cvt_w + 8192 cvt_x) over blocks 1..511
#pragma unroll 1
    for (int k = 0; k < 19; ++k) {
      int unit = (blockIdx.x - 1) + 511 * k;
      if (unit >= 9216) break;
      if (unit < 1024) {
        int i = unit * 256 + tid;
        int idx = i * 4;
        int n = idx >> 9, kk = idx & 511;
        const float* src;
        ushort* dst;
        if (n < 512)       { src = Wq + (size_t)n * 512 + kk;          dst = Wcat + (size_t)n * 512 + kk; }
        else if (n < 1024) { src = Wk + (size_t)(n - 512) * 512 + kk;  dst = Wcat + (size_t)n * 512 + kk; }
        else if (n < 1536) { src = Wv + (size_t)(n - 1024) * 512 + kk; dst = Wcat + (size_t)n * 512 + kk; }
        else               { src = Wo + (size_t)(n - 1536) * 512 + kk; dst = Wob + (size_t)(n - 1536) * 512 + kk; }
        float4 v = *(const float4*)src;
        ushort4 o = {f2bf(v.x), f2bf(v.y), f2bf(v.z), f2bf(v.w)};
        *(ushort4*)dst = o;
      } else {
        int i = (unit - 1024) * 256 + tid;  // token-order x -> bf16
        float4 v = ((const float4*)x)[i];
        ushort4 o = {f2bf(v.x), f2bf(v.y), f2bf(v.z), f2bf(v.w)};
        ((ushort4*)xb)[i] = o;
      }
    }
  }
  grid_bar(&bars[0]);

  // ================= phase 1: QKV GEMM, 3 tiles/block (round-17 body) ===========
  {
    ushort* sAb = (ushort*)ldsraw;
    ushort* sBb = (ushort*)(ldsraw + 32768);
    const int wr = wave >> 1, wc = wave & 1;
    const int rowS = wave * 32 + (lane >> 3);
    const int kc = lane & 7;
    constexpr int NK = Kdim / 64;
#pragma unroll 1
    for (int t = blockIdx.x; t < 1536; t += NBLK) {
      const int xcd = t & 7, gl = t >> 3;
      const int mbase = (xcd * 16 + (gl & 15)) * 128;
      const int nbase = (gl >> 4) * 128;
      const int mb_hi = mbase & ~(Sc - 1);
      f32x4 acc[4][4] = {};
      int arow[4];
#pragma unroll
      for (int c = 0; c < 4; ++c)
        arow[c] = mb_hi | perm[(mbase + rowS + c * 8) & (Sc - 1)];

      auto stage = [&](int buf, int kt) {
        const int k0 = kt * 64;
#pragma unroll
        for (int c = 0; c < 4; ++c) {
          int row = rowS + c * 8;
          int kcp = (kc ^ (row & 7)) * 8;
          gload16(xb + (size_t)arow[c] * Kdim + k0 + kcp,
                  sAb + buf * 8192 + (wave * 256 + c * 64) * 8);
          gload16(Wcat + (size_t)(nbase + row) * Kdim + k0 + kcp,
                  sBb + buf * 8192 + (wave * 256 + c * 64) * 8);
        }
      };

      stage(0, 0);
      stage(1, 1);
      for (int kt = 0; kt < NK; ++kt) {
        const int cur = kt & 1;
        if (kt < NK - 1) {
          WAIT_VM_BARRIER(8);
        } else {
          WAIT_VM_BARRIER(0);
        }
        const char* Ab = (const char*)(sAb + cur * 8192);
        const char* Bb = (const char*)(sBb + cur * 8192);
        __builtin_amdgcn_s_setprio(1);
#pragma unroll
        for (int kk = 0; kk < 2; ++kk) {
          bf16x8 af[4], bfv[4];
#pragma unroll
          for (int i = 0; i < 4; ++i) {
            int row = wr * 64 + i * 16 + (lane & 15);
            int off = row * 128 + kk * 64 + (lane >> 4) * 16;
            off ^= (row & 7) << 4;
            af[i] = *(const bf16x8*)(Ab + off);
          }
#pragma unroll
          for (int j = 0; j < 4; ++j) {
            int col = wc * 64 + j * 16 + (lane & 15);
            int off = col * 128 + kk * 64 + (lane >> 4) * 16;
            off ^= (col & 7) << 4;
            bfv[j] = *(const bf16x8*)(Bb + off);
          }
#pragma unroll
          for (int i = 0; i < 4; ++i)
#pragma unroll
            for (int j = 0; j < 4; ++j)
              acc[i][j] = __builtin_amdgcn_mfma_f32_16x16x32_bf16(af[i], bfv[j], acc[i][j], 0, 0, 0);
        }
        __builtin_amdgcn_s_setprio(0);
        WAIT_LGKM_BARRIER();
        if (kt + 2 < NK) stage(cur, kt + 2);
      }

      // LDS-bounce epilogue: T[128][136]
      {
        ushort* T = (ushort*)ldsraw;
#pragma unroll
        for (int i = 0; i < 4; ++i) {
#pragma unroll
          for (int j = 0; j < 4; ++j) {
            int nl = wc * 64 + j * 16 + (lane & 15);
            int n = nbase + nl;
            float bvv = (n < 512) ? bq[n] : (n < 1024) ? bk[n - 512] : bv[n - 1024];
#pragma unroll
            for (int r = 0; r < 4; ++r) {
              int ml = wr * 64 + i * 16 + (lane >> 4) * 4 + r;
              T[ml * 136 + nl] = f2bf(acc[i][j][r] + bvv);
            }
          }
        }
        __syncthreads();
#pragma unroll
        for (int k = 0; k < 8; ++k) {
          int c = tid + 256 * k;
          int row = c >> 4, col8 = (c & 15) * 8;
          uint4 w = *(const uint4*)(T + row * 136 + col8);
          int n0 = nbase + col8;
          int proj = n0 >> 9, h = (n0 >> 6) & 7, d0 = n0 & 63;
          int p = mbase + row;
          int bidx = p >> 11, pl = p & (Sc - 1);
          size_t off = (size_t)proj * ((size_t)Bc * Hc * Sc * HDc) +
                       (size_t)((bidx * Hc + h) * Sc + pl) * HDc + d0;
          *(uint4*)(qkv + off) = w;
        }
      }
      __syncthreads();  // all T reads done before next tile restages LDS
    }
  }
  grid_bar(&bars[1]);

  // ================= phase 2: attention, grid-strided 4-wave packing ============
  {
    const int NIT = *nitems;
    ushort* vt = (ushort*)(ldsraw + wave * 5120);  // 64*40 ushorts per wave
    const int ql = lane & 15, lg = lane >> 4;
    const size_t planeSz = (size_t)Bc * Hc * Sc * HDc;
    const int vk = lane & 31;
    const int vh = (lane >> 5) * 32;
    const int Lbase = 4 * (ql + 32 * (lg & 1));
#pragma unroll 1
    for (int k = 0; k < 4; ++k) {
      const int u = (blockIdx.x * 4 + wave) + 2048 * k;
      const int item = u & (MAXITEMS - 1);
      const int bh = u >> 7;
      if (item >= NIT) continue;
      const int iv = items[item];
      const int g = iv >> 16, q0 = iv & 0xffff;
      const int start = gstart[g], n = gsz[g];
      const ushort* qb = qkv + (size_t)bh * Sc * HDc;
      const ushort* kb = qb + planeSz;
      const ushort* vb = kb + planeSz;

      bf16x8 qf[2][2];
#pragma unroll
      for (int qt = 0; qt < 2; ++qt) {
        int row = min(start + q0 + qt * 16 + ql, Sc - 1);
#pragma unroll
        for (int h = 0; h < 2; ++h)
          qf[qt][h] = *(const bf16x8*)(qb + (size_t)row * HDc + h * 32 + lg * 8);
      }
      f32x4 oacc[2][4] = {};
      float lsum[2] = {0.f, 0.f};
      const int npair = (n + 31) >> 5;
      for (int pr = 0; pr < npair; ++pr) {
        const int c0 = pr * 32;
        int vrow = min(start + c0 + vk, Sc - 1);
        const uint4* vp = (const uint4*)(vb + (size_t)vrow * HDc + vh);
        uint4 v0 = vp[0], v1 = vp[1], v2 = vp[2], v3 = vp[3];
        bf16x8 kf[2][2];
#pragma unroll
        for (int t2 = 0; t2 < 2; ++t2) {
          int row = min(start + c0 + t2 * 16 + ql, Sc - 1);
#pragma unroll
          for (int h = 0; h < 2; ++h)
            kf[t2][h] = *(const bf16x8*)(kb + (size_t)row * HDc + h * 32 + lg * 8);
        }
        uint pw[2][4];
#pragma unroll
        for (int qt = 0; qt < 2; ++qt) {
          f32x4 s0 = {}, s1 = {};
          s0 = __builtin_amdgcn_mfma_f32_16x16x32_bf16(kf[0][0], qf[qt][0], s0, 0, 0, 0);
          s0 = __builtin_amdgcn_mfma_f32_16x16x32_bf16(kf[0][1], qf[qt][1], s0, 0, 0, 0);
          s1 = __builtin_amdgcn_mfma_f32_16x16x32_bf16(kf[1][0], qf[qt][0], s1, 0, 0, 0);
          s1 = __builtin_amdgcn_mfma_f32_16x16x32_bf16(kf[1][1], qf[qt][1], s1, 0, 0, 0);
          float p0[4], p1[4];
          float ls = 0.f;
#pragma unroll
          for (int r = 0; r < 4; ++r) {
            int kk = c0 + 4 * lg + r;
            float e0 = (kk < n) ? __expf(s0[r] * 0.125f) : 0.f;
            float e1 = (kk + 16 < n) ? __expf(s1[r] * 0.125f) : 0.f;
            p0[r] = e0;
            p1[r] = e1;
            ls += e0 + e1;
          }
          lsum[qt] += ls;
          uint a0 = cvtpk(p0[0], p0[1]), b0 = cvtpk(p0[2], p0[3]);
          uint a1 = cvtpk(p1[0], p1[1]), b1 = cvtpk(p1[2], p1[3]);
          uint pA0 = __builtin_amdgcn_ds_bpermute(Lbase, a0);
          uint pB0 = __builtin_amdgcn_ds_bpermute(Lbase, b0);
          uint pA1 = __builtin_amdgcn_ds_bpermute(Lbase, a1);
          uint pB1 = __builtin_amdgcn_ds_bpermute(Lbase, b1);
          uint pC0 = __builtin_amdgcn_ds_bpermute(Lbase + 64, a0);
          uint pD0 = __builtin_amdgcn_ds_bpermute(Lbase + 64, b0);
          uint pC1 = __builtin_amdgcn_ds_bpermute(Lbase + 64, a1);
          uint pD1 = __builtin_amdgcn_ds_bpermute(Lbase + 64, b1);
          bool t0 = lg < 2;
          pw[qt][0] = t0 ? pA0 : pA1;
          pw[qt][1] = t0 ? pB0 : pB1;
          pw[qt][2] = t0 ? pC0 : pC1;
          pw[qt][3] = t0 ? pD0 : pD1;
        }
        {
          uint w[16] = {v0.x, v0.y, v0.z, v0.w, v1.x, v1.y, v1.z, v1.w,
                        v2.x, v2.y, v2.z, v2.w, v3.x, v3.y, v3.z, v3.w};
#pragma unroll
          for (int i = 0; i < 16; ++i) {
            vt[(vh + 2 * i) * 40 + vk] = (ushort)(w[i] & 0xffffu);
            vt[(vh + 2 * i + 1) * 40 + vk] = (ushort)(w[i] >> 16);
          }
        }
        asm volatile("s_waitcnt lgkmcnt(0)" ::: "memory");
        __builtin_amdgcn_sched_barrier(0);
        bf16x8 vf[4];
#pragma unroll
        for (int dq = 0; dq < 4; ++dq)
          vf[dq] = *(const bf16x8*)(vt + (dq * 16 + ql) * 40 + lg * 8);
        asm volatile("s_waitcnt lgkmcnt(0)" ::: "memory");
        __builtin_amdgcn_sched_barrier(0);
#pragma unroll
        for (int qt = 0; qt < 2; ++qt) {
          union { uint u4[4]; bf16x8 v; } pf;
          pf.u4[0] = pw[qt][0]; pf.u4[1] = pw[qt][1]; pf.u4[2] = pw[qt][2]; pf.u4[3] = pw[qt][3];
#pragma unroll
          for (int dq = 0; dq < 4; ++dq)
            oacc[qt][dq] = __builtin_amdgcn_mfma_f32_16x16x32_bf16(vf[dq], pf.v, oacc[qt][dq], 0, 0, 0);
        }
      }
#pragma unroll
      for (int qt = 0; qt < 2; ++qt) {
        float l = lsum[qt];
        l += __shfl_xor(l, 16);
        l += __shfl_xor(l, 32);
        float inv = 1.f / l;
        int qi = q0 + qt * 16 + ql;
        if (qi < n) {
          int p = start + qi;
          ushort* op = obuf + (size_t)((bh >> 3) * Sc + p) * Ec + (bh & 7) * HDc + lg * 4;
#pragma unroll
          for (int dq = 0; dq < 4; ++dq) {
            uint w0 = cvtpk(oacc[qt][dq][0] * inv, oacc[qt][dq][1] * inv);
            uint w1 = cvtpk(oacc[qt][dq][2] * inv, oacc[qt][dq][3] * inv);
            uint2 wv2 = {w0, w1};
            *(uint2*)(op + dq * 16) = wv2;
          }
        }
      }
    }
  }
  grid_bar(&bars[2]);

  // ================= phase 3: out-proj GEMM, 1 tile/block (round-17 body) =======
  {
    constexpr int NK = Kdim / 64;
    constexpr int NTOT = 512;
    ushort* sAb = (ushort*)ldsraw;
    ushort* sBb = (ushort*)(ldsraw + 32768);
    const int wr = wave >> 1, wc = wave & 1;
    const int t = blockIdx.x;
    const int xcd = t & 7, gl = t >> 3;
    const int mbase = (xcd * 16 + (gl & 15)) * 128;
    const int nbase = (gl >> 4) * 128;
    f32x4 acc[4][4] = {};
    const int rowS = wave * 32 + (lane >> 3);
    const int kc = lane & 7;

    auto stage = [&](int buf, int kt) {
      const int k0 = kt * 64;
#pragma unroll
      for (int c = 0; c < 4; ++c) {
        int row = rowS + c * 8;
        int kcp = (kc ^ (row & 7)) * 8;
        gload16(obuf + (size_t)(mbase + row) * Kdim + k0 + kcp,
                sAb + buf * 8192 + (wave * 256 + c * 64) * 8);
        gload16(Wob + (size_t)(nbase + row) * Kdim + k0 + kcp,
                sBb + buf * 8192 + (wave * 256 + c * 64) * 8);
      }
    };

    stage(0, 0);
    stage(1, 1);
    for (int kt = 0; kt < NK; ++kt) {
      const int cur = kt & 1;
      if (kt < NK - 1) {
        WAIT_VM_BARRIER(8);
      } else {
        WAIT_VM_BARRIER(0);
      }
      const char* Ab = (const char*)(sAb + cur * 8192);
      const char* Bb = (const char*)(sBb + cur * 8192);
      __builtin_amdgcn_s_setprio(1);
#pragma unroll
      for (int kk = 0; kk < 2; ++kk) {
        bf16x8 af[4], bfv[4];
#pragma unroll
        for (int i = 0; i < 4; ++i) {
          int row = wr * 64 + i * 16 + (lane & 15);
          int off = row * 128 + kk * 64 + (lane >> 4) * 16;
          off ^= (row & 7) << 4;
          af[i] = *(const bf16x8*)(Ab + off);
        }
#pragma unroll
        for (int j = 0; j < 4; ++j) {
          int col = wc * 64 + j * 16 + (lane & 15);
          int off = col * 128 + kk * 64 + (lane >> 4) * 16;
          off ^= (col & 7) << 4;
          bfv[j] = *(const bf16x8*)(Bb + off);
        }
#pragma unroll
        for (int i = 0; i < 4; ++i)
#pragma unroll
          for (int j = 0; j < 4; ++j)
            acc[i][j] = __builtin_amdgcn_mfma_f32_16x16x32_bf16(af[i], bfv[j], acc[i][j], 0, 0, 0);
      }
      __builtin_amdgcn_s_setprio(0);
      WAIT_LGKM_BARRIER();
      if (kt + 2 < NK) stage(cur, kt + 2);
    }

    float* T = (float*)ldsraw;
#pragma unroll
    for (int i = 0; i < 4; ++i) {
#pragma unroll
      for (int j = 0; j < 4; ++j) {
        int nl = wc * 64 + j * 16 + (lane & 15);
        float bvv = bo[nbase + nl];
#pragma unroll
        for (int r = 0; r < 4; ++r) {
          int ml = wr * 64 + i * 16 + (lane >> 4) * 4 + r;
          T[ml * 128 + nl] = acc[i][j][r] + bvv;
        }
      }
    }
    __syncthreads();
#pragma unroll
    for (int k = 0; k < 16; ++k) {
      int c = tid + 256 * k;
      int row = c >> 5, col4 = (c & 31) * 4;
      float4 w = *(const float4*)(T + row * 128 + col4);
      int p = mbase + row;
      int bidx = p >> 11;
      int orow = (bidx << 11) | perm[p & (Sc - 1)];
      *(float4*)(out + (size_t)orow * NTOT + nbase + col4) = w;
    }
  }
}

extern "C" void kernel_launch(void* const* d_in, const int* in_sizes, int n_in,
                              void* d_out, int out_size, void* d_ws, size_t ws_size,
                              hipStream_t stream) {
  const float* x  = (const float*)d_in[0];
  const float* Wq = (const float*)d_in[1];
  const float* bq = (const float*)d_in[2];
  const float* Wk = (const float*)d_in[3];
  const float* bk = (const float*)d_in[4];
  const float* Wv = (const float*)d_in[5];
  const float* bv = (const float*)d_in[6];
  const float* Wo = (const float*)d_in[7];
  const float* bo = (const float*)d_in[8];
  const int* ids  = (const int*)d_in[9];
  float* out = (float*)d_out;

  char* ws = (char*)d_ws;
  ushort* xb   = (ushort*)(ws);
  ushort* Wcat = (ushort*)(ws + 16777216);
  ushort* Wob  = (ushort*)(ws + 18350080);
  ushort* qkv  = (ushort*)(ws + 18874368);
  ushort* obuf = (ushort*)(ws + 69206016);
  int* perm    = (int*)(ws + 85983232);
  int* gstart  = perm + Sc;
  int* gsz     = gstart + NI;
  int* items   = gsz + NI;
  int* nitems  = items + MAXITEMS;
  int* bars    = nitems + 1;

  (void)hipMemsetAsync(bars, 0, 3 * sizeof(int), stream);
  mega_kernel<<<dim3(NBLK), dim3(256), 0, stream>>>(
      ids, x, Wq, Wk, Wv, Wo, bq, bk, bv, bo, xb, Wcat, Wob, qkv, obuf,
      perm, gstart, gsz, items, nitems, out, bars);
}

// Round 21
// 118.150 us; speedup vs baseline: 2.4702x; 2.4702x over previous
//
#include <hip/hip_runtime.h>
#include <cstdint>

#define DEVFN __device__ __forceinline__

typedef __bf16 bf16x8 __attribute__((ext_vector_type(8)));
typedef float f32x4 __attribute__((ext_vector_type(4)));
typedef unsigned int uint;

constexpr int Bc = 8, Sc = 2048, Ec = 512, Hc = 8, HDc = 64, NI = 64;
constexpr int Mtot = Bc * Sc;  // 16384
constexpr int Kdim = Ec;       // 512
constexpr int MAXITEMS = 128;  // sum ceil(n_g/32) <= 64 + 2048/32 = 128

DEVFN unsigned short f2bf(float f) {
  unsigned u = __builtin_bit_cast(unsigned, f);
  u += 0x7fffu + ((u >> 16) & 1u);  // RNE (inputs finite)
  return (unsigned short)(u >> 16);
}

typedef const void __attribute__((address_space(1))) gvoid_t;
typedef void __attribute__((address_space(3))) lvoid_t;
DEVFN void gload16(const void* g, void* l) {
  __builtin_amdgcn_global_load_lds((gvoid_t*)g, (lvoid_t*)l, 16, 0, 0);
}

DEVFN uint cvtpk(float lo, float hi) {
  uint r;
  asm("v_cvt_pk_bf16_f32 %0, %1, %2" : "=v"(r) : "v"(lo), "v"(hi));
  return r;
}

// Fused waitcnt+barrier: single asm with "memory" clobber = full compiler memory
// fence around the HW barrier (raw s_barrier builtin is not an IR fence).
#define WAIT_VM_BARRIER(N)                                            \
  do {                                                                \
    asm volatile("s_waitcnt vmcnt(" #N ")\n\ts_barrier" ::: "memory"); \
    __builtin_amdgcn_sched_barrier(0);                                \
  } while (0)
#define WAIT_LGKM_BARRIER()                                            \
  do {                                                                 \
    asm volatile("s_waitcnt lgkmcnt(0)\n\ts_barrier" ::: "memory");    \
    __builtin_amdgcn_sched_barrier(0);                                 \
  } while (0)

// ---------------- prep2: sort (block 0) | cvt_w (1024 blocks) | cvt_x (8192) -----
__global__ void prep2_kernel(const int* __restrict__ ids, int* __restrict__ perm,
                             int* __restrict__ gstart, int* __restrict__ gsz,
                             int* __restrict__ items, int* __restrict__ nitems,
                             const float* __restrict__ Wq, const float* __restrict__ Wk,
                             const float* __restrict__ Wv, const float* __restrict__ Wo,
                             ushort* __restrict__ Wcat, ushort* __restrict__ Wob,
                             const float* __restrict__ x, ushort* __restrict__ xb) {
  if (blockIdx.x == 0) {
    __shared__ int sid[Sc];
    __shared__ int hist[NI];
    __shared__ int base[NI];
    int t = threadIdx.x;  // 256 threads
    if (t < NI) hist[t] = 0;
    for (int i = t; i < Sc; i += 256) sid[i] = ids[i];
    __syncthreads();
    for (int i = t; i < Sc; i += 256) atomicAdd(&hist[sid[i]], 1);
    __syncthreads();
    if (t == 0) {
      int run = 0;
      for (int g = 0; g < NI; ++g) { base[g] = run; run += hist[g]; }
      int cnt = 0;
      for (int g = 0; g < NI; ++g)
        for (int q0 = 0; q0 < hist[g]; q0 += 32) items[cnt++] = (g << 16) | q0;
      *nitems = cnt;
    }
    __syncthreads();
    if (t < NI) { gstart[t] = base[t]; gsz[t] = hist[t]; }
    int lane = t & 63, w = t >> 6;
    for (int g = w; g < NI; g += 4) {
      int run = base[g];
      for (int c = 0; c < Sc; c += 64) {
        int tok = c + lane;
        int id = sid[tok];
        unsigned long long mask = __ballot(id == g);
        if (id == g) {
          int rank = __popcll(mask & ((1ull << lane) - 1ull));
          perm[run + rank] = tok;
        }
        run += __popcll(mask);
      }
    }
  } else if (blockIdx.x <= 1024) {
    int i = (blockIdx.x - 1) * 256 + threadIdx.x;
    int idx = i * 4;
    int n = idx >> 9, k = idx & 511;
    const float* src;
    ushort* dst;
    if (n < 512)       { src = Wq + (size_t)n * 512 + k;          dst = Wcat + (size_t)n * 512 + k; }
    else if (n < 1024) { src = Wk + (size_t)(n - 512) * 512 + k;  dst = Wcat + (size_t)n * 512 + k; }
    else if (n < 1536) { src = Wv + (size_t)(n - 1024) * 512 + k; dst = Wcat + (size_t)n * 512 + k; }
    else               { src = Wo + (size_t)(n - 1536) * 512 + k; dst = Wob + (size_t)(n - 1536) * 512 + k; }
    float4 v = *(const float4*)src;
    ushort4 o = {f2bf(v.x), f2bf(v.y), f2bf(v.z), f2bf(v.w)};
    *(ushort4*)dst = o;
  } else {
    // cvt_x, TOKEN order: xb[i] = bf16(x[i]) elementwise (4-float chunks)
    int i = (blockIdx.x - 1025) * 256 + threadIdx.x;
    float4 v = ((const float4*)x)[i];
    ushort4 o = {f2bf(v.x), f2bf(v.y), f2bf(v.z), f2bf(v.w)};
    ((ushort4*)xb)[i] = o;
  }
}

// ---------------- QKV GEMM: 128x128, counted-vmcnt, perm-indirect A staging ------
__global__ __launch_bounds__(256) void gemm_qkv128(
    const ushort* __restrict__ A, const ushort* __restrict__ Bw,
    const float* __restrict__ bias0, const float* __restrict__ bias1,
    const float* __restrict__ bias2, const int* __restrict__ permarg,
    ushort* __restrict__ qkvout) {
  constexpr int NK = Kdim / 64;  // 8
  __shared__ __align__(16) char ldsraw[65536];
  ushort* sAb = (ushort*)ldsraw;             // [2][128*64]
  ushort* sBb = (ushort*)(ldsraw + 32768);   // [2][128*64]
  const int tid = threadIdx.x;
  const int lane = tid & 63;
  const int wave = tid >> 6;
  const int wr = wave >> 1, wc = wave & 1;
  const int orig = blockIdx.x;
  const int xcd = orig & 7, gl = orig >> 3;
  const int mbase = (xcd * 16 + (gl & 15)) * 128;
  const int nbase = (gl >> 4) * 128;

  f32x4 acc[4][4] = {};

  const int rowS = wave * 32 + (lane >> 3);  // staging row (+ c*8), sorted space
  const int kc = lane & 7;                   // staging 16B chunk within row
  const int mb_hi = mbase & ~(Sc - 1);       // batch base (tile never crosses batch)

  int arow[4];
#pragma unroll
  for (int c = 0; c < 4; ++c)
    arow[c] = mb_hi | permarg[(mbase + rowS + c * 8) & (Sc - 1)];

  auto stage = [&](int buf, int kt) {  // 8 gload16 per thread (4 A + 4 B)
    const int k0 = kt * 64;
#pragma unroll
    for (int c = 0; c < 4; ++c) {
      int row = rowS + c * 8;
      int kcp = (kc ^ (row & 7)) * 8;  // pre-swizzled source -> linear LDS dest
      gload16(A + (size_t)arow[c] * Kdim + k0 + kcp,
              sAb + buf * 8192 + (wave * 256 + c * 64) * 8);
      gload16(Bw + (size_t)(nbase + row) * Kdim + k0 + kcp,
              sBb + buf * 8192 + (wave * 256 + c * 64) * 8);
    }
  };

  stage(0, 0);
  stage(1, 1);  // 16 loads in flight

  for (int kt = 0; kt < NK; ++kt) {
    const int cur = kt & 1;
    if (kt < NK - 1) {
      WAIT_VM_BARRIER(8);   // my tile-kt loads done; all waves' visible after barrier
    } else {
      WAIT_VM_BARRIER(0);
    }

    const char* Ab = (const char*)(sAb + cur * 8192);
    const char* Bb = (const char*)(sBb + cur * 8192);
    __builtin_amdgcn_s_setprio(1);
#pragma unroll
    for (int kk = 0; kk < 2; ++kk) {
      bf16x8 af[4], bfv[4];
#pragma unroll
      for (int i = 0; i < 4; ++i) {
        int row = wr * 64 + i * 16 + (lane & 15);
        int off = row * 128 + kk * 64 + (lane >> 4) * 16;
        off ^= (row & 7) << 4;
        af[i] = *(const bf16x8*)(Ab + off);
      }
#pragma unroll
      for (int j = 0; j < 4; ++j) {
        int col = wc * 64 + j * 16 + (lane & 15);
        int off = col * 128 + kk * 64 + (lane >> 4) * 16;
        off ^= (col & 7) << 4;
        bfv[j] = *(const bf16x8*)(Bb + off);
      }
#pragma unroll
      for (int i = 0; i < 4; ++i)
#pragma unroll
        for (int j = 0; j < 4; ++j)
          acc[i][j] = __builtin_amdgcn_mfma_f32_16x16x32_bf16(af[i], bfv[j], acc[i][j], 0, 0, 0);
    }
    __builtin_amdgcn_s_setprio(0);

    WAIT_LGKM_BARRIER();    // all waves done reading buf cur
    if (kt + 2 < NK) stage(cur, kt + 2);  // overwrite just-read buffer
  }

  // LDS-bounce epilogue: T[128][136] ushort (16B-aligned rows, <=2-way banks)
  {
    ushort* T = (ushort*)ldsraw;
#pragma unroll
    for (int i = 0; i < 4; ++i) {
#pragma unroll
      for (int j = 0; j < 4; ++j) {
        int nl = wc * 64 + j * 16 + (lane & 15);
        int n = nbase + nl;
        float bv = (n < 512) ? bias0[n] : (n < 1024) ? bias1[n - 512] : bias2[n - 1024];
#pragma unroll
        for (int r = 0; r < 4; ++r) {
          int ml = wr * 64 + i * 16 + (lane >> 4) * 4 + r;
          T[ml * 136 + nl] = f2bf(acc[i][j][r] + bv);
        }
      }
    }
    __syncthreads();
#pragma unroll
    for (int k = 0; k < 8; ++k) {
      int c = tid + 256 * k;
      int row = c >> 4, col8 = (c & 15) * 8;
      uint4 w = *(const uint4*)(T + row * 136 + col8);
      int n0 = nbase + col8;
      int proj = n0 >> 9, h = (n0 >> 6) & 7, d0 = n0 & 63;
      int p = mbase + row;
      int bidx = p >> 11, pl = p & (Sc - 1);
      size_t off = (size_t)proj * ((size_t)Bc * Hc * Sc * HDc) +
                   (size_t)((bidx * Hc + h) * Sc + pl) * HDc + d0;
      *(uint4*)(qkvout + off) = w;  // coalesced 16B, full-line coverage
    }
  }
}

// ---------------- out-proj GEMM: 128x128, counted-vmcnt pipeline ------------------
__global__ __launch_bounds__(256) void gemm_out128(
    const ushort* __restrict__ A, const ushort* __restrict__ Bw,
    const float* __restrict__ bias0, const int* __restrict__ permarg,
    float* __restrict__ out) {
  constexpr int NK = Kdim / 64;  // 8
  constexpr int NTOT = 512;
  __shared__ __align__(16) char ldsraw[65536];
  ushort* sAb = (ushort*)ldsraw;             // [2][128*64]
  ushort* sBb = (ushort*)(ldsraw + 32768);   // [2][128*64]
  const int tid = threadIdx.x;
  const int lane = tid & 63;
  const int wave = tid >> 6;
  const int wr = wave >> 1, wc = wave & 1;
  const int orig = blockIdx.x;
  const int xcd = orig & 7, gl = orig >> 3;
  const int mbase = (xcd * 16 + (gl & 15)) * 128;
  const int nbase = (gl >> 4) * 128;

  f32x4 acc[4][4] = {};

  const int rowS = wave * 32 + (lane >> 3);
  const int kc = lane & 7;

  auto stage = [&](int buf, int kt) {
    const int k0 = kt * 64;
#pragma unroll
    for (int c = 0; c < 4; ++c) {
      int row = rowS + c * 8;
      int kcp = (kc ^ (row & 7)) * 8;
      gload16(A + (size_t)(mbase + row) * Kdim + k0 + kcp,
              sAb + buf * 8192 + (wave * 256 + c * 64) * 8);
      gload16(Bw + (size_t)(nbase + row) * Kdim + k0 + kcp,
              sBb + buf * 8192 + (wave * 256 + c * 64) * 8);
    }
  };

  stage(0, 0);
  stage(1, 1);

  for (int kt = 0; kt < NK; ++kt) {
    const int cur = kt & 1;
    if (kt < NK - 1) {
      WAIT_VM_BARRIER(8);
    } else {
      WAIT_VM_BARRIER(0);
    }

    const char* Ab = (const char*)(sAb + cur * 8192);
    const char* Bb = (const char*)(sBb + cur * 8192);
    __builtin_amdgcn_s_setprio(1);
#pragma unroll
    for (int kk = 0; kk < 2; ++kk) {
      bf16x8 af[4], bfv[4];
#pragma unroll
      for (int i = 0; i < 4; ++i) {
        int row = wr * 64 + i * 16 + (lane & 15);
        int off = row * 128 + kk * 64 + (lane >> 4) * 16;
        off ^= (row & 7) << 4;
        af[i] = *(const bf16x8*)(Ab + off);
      }
#pragma unroll
      for (int j = 0; j < 4; ++j) {
        int col = wc * 64 + j * 16 + (lane & 15);
        int off = col * 128 + kk * 64 + (lane >> 4) * 16;
        off ^= (col & 7) << 4;
        bfv[j] = *(const bf16x8*)(Bb + off);
      }
#pragma unroll
      for (int i = 0; i < 4; ++i)
#pragma unroll
        for (int j = 0; j < 4; ++j)
          acc[i][j] = __builtin_amdgcn_mfma_f32_16x16x32_bf16(af[i], bfv[j], acc[i][j], 0, 0, 0);
    }
    __builtin_amdgcn_s_setprio(0);

    WAIT_LGKM_BARRIER();
    if (kt + 2 < NK) stage(cur, kt + 2);
  }

  float* T = (float*)ldsraw;  // [128][128] f32
#pragma unroll
  for (int i = 0; i < 4; ++i) {
#pragma unroll
    for (int j = 0; j < 4; ++j) {
      int nl = wc * 64 + j * 16 + (lane & 15);
      float bv = bias0[nbase + nl];
#pragma unroll
      for (int r = 0; r < 4; ++r) {
        int ml = wr * 64 + i * 16 + (lane >> 4) * 4 + r;
        T[ml * 128 + nl] = acc[i][j][r] + bv;
      }
    }
  }
  __syncthreads();
#pragma unroll
  for (int k = 0; k < 16; ++k) {
    int c = tid + 256 * k;
    int row = c >> 5, col4 = (c & 31) * 4;
    float4 w = *(const float4*)(T + row * 128 + col4);
    int p = mbase + row;
    int bidx = p >> 11;
    int orow = (bidx << 11) | permarg[p & (Sc - 1)];
    *(float4*)(out + (size_t)orow * NTOT + nbase + col4) = w;
  }
}

// ---------------- MFMA attention: 1 wave = (bh, 32-query chunk of one group) -------
__global__ __launch_bounds__(64) void attn5_kernel(
    const ushort* __restrict__ qkv, const int* __restrict__ gstart,
    const int* __restrict__ gsz, const int* __restrict__ items,
    const int* __restrict__ nitems, ushort* __restrict__ obuf) {
  __shared__ __align__(16) ushort vt[64 * 40];  // Vt[d][k], rows padded to 40 ushorts (80B)
  if ((int)blockIdx.x >= *nitems) return;
  const int iv = items[blockIdx.x];
  const int g = iv >> 16, q0 = iv & 0xffff;
  const int bh = blockIdx.y;
  const int start = gstart[g], n = gsz[g];
  const int lane = threadIdx.x;
  const int ql = lane & 15, lg = lane >> 4;

  const size_t planeSz = (size_t)Bc * Hc * Sc * HDc;
  const ushort* qb = qkv + (size_t)bh * Sc * HDc;
  const ushort* kb = qb + planeSz;
  const ushort* vb = kb + planeSz;

  bf16x8 qf[2][2];
#pragma unroll
  for (int qt = 0; qt < 2; ++qt) {
    int row = min(start + q0 + qt * 16 + ql, Sc - 1);
#pragma unroll
    for (int h = 0; h < 2; ++h)
      qf[qt][h] = *(const bf16x8*)(qb + (size_t)row * HDc + h * 32 + lg * 8);
  }

  f32x4 oacc[2][4] = {};
  float lsum[2] = {0.f, 0.f};

  const int vk = lane & 31;
  const int vh = (lane >> 5) * 32;
  const int Lbase = 4 * (ql + 32 * (lg & 1));

  const int npair = (n + 31) >> 5;
  for (int pr = 0; pr < npair; ++pr) {
    const int c0 = pr * 32;
    int vrow = min(start + c0 + vk, Sc - 1);
    const uint4* vp = (const uint4*)(vb + (size_t)vrow * HDc + vh);
    uint4 v0 = vp[0], v1 = vp[1], v2 = vp[2], v3 = vp[3];

    bf16x8 kf[2][2];
#pragma unroll
    for (int t = 0; t < 2; ++t) {
      int row = min(start + c0 + t * 16 + ql, Sc - 1);
#pragma unroll
      for (int h = 0; h < 2; ++h)
        kf[t][h] = *(const bf16x8*)(kb + (size_t)row * HDc + h * 32 + lg * 8);
    }

    uint pw[2][4];
#pragma unroll
    for (int qt = 0; qt < 2; ++qt) {
      f32x4 s0 = {}, s1 = {};
      s0 = __builtin_amdgcn_mfma_f32_16x16x32_bf16(kf[0][0], qf[qt][0], s0, 0, 0, 0);
      s0 = __builtin_amdgcn_mfma_f32_16x16x32_bf16(kf[0][1], qf[qt][1], s0, 0, 0, 0);
      s1 = __builtin_amdgcn_mfma_f32_16x16x32_bf16(kf[1][0], qf[qt][0], s1, 0, 0, 0);
      s1 = __builtin_amdgcn_mfma_f32_16x16x32_bf16(kf[1][1], qf[qt][1], s1, 0, 0, 0);
      float p0[4], p1[4];
      float ls = 0.f;
#pragma unroll
      for (int r = 0; r < 4; ++r) {
        int kk = c0 + 4 * lg + r;
        float e0 = (kk < n) ? __expf(s0[r] * 0.125f) : 0.f;
        float e1 = (kk + 16 < n) ? __expf(s1[r] * 0.125f) : 0.f;
        p0[r] = e0;
        p1[r] = e1;
        ls += e0 + e1;
      }
      lsum[qt] += ls;
      uint a0 = cvtpk(p0[0], p0[1]), b0 = cvtpk(p0[2], p0[3]);
      uint a1 = cvtpk(p1[0], p1[1]), b1 = cvtpk(p1[2], p1[3]);
      uint pA0 = __builtin_amdgcn_ds_bpermute(Lbase, a0);
      uint pB0 = __builtin_amdgcn_ds_bpermute(Lbase, b0);
      uint pA1 = __builtin_amdgcn_ds_bpermute(Lbase, a1);
      uint pB1 = __builtin_amdgcn_ds_bpermute(Lbase, b1);
      uint pC0 = __builtin_amdgcn_ds_bpermute(Lbase + 64, a0);
      uint pD0 = __builtin_amdgcn_ds_bpermute(Lbase + 64, b0);
      uint pC1 = __builtin_amdgcn_ds_bpermute(Lbase + 64, a1);
      uint pD1 = __builtin_amdgcn_ds_bpermute(Lbase + 64, b1);
      bool t0 = lg < 2;
      pw[qt][0] = t0 ? pA0 : pA1;
      pw[qt][1] = t0 ? pB0 : pB1;
      pw[qt][2] = t0 ? pC0 : pC1;
      pw[qt][3] = t0 ? pD0 : pD1;
    }

    {
      uint w[16] = {v0.x, v0.y, v0.z, v0.w, v1.x, v1.y, v1.z, v1.w,
                    v2.x, v2.y, v2.z, v2.w, v3.x, v3.y, v3.z, v3.w};
#pragma unroll
      for (int i = 0; i < 16; ++i) {
        vt[(vh + 2 * i) * 40 + vk] = (ushort)(w[i] & 0xffffu);
        vt[(vh + 2 * i + 1) * 40 + vk] = (ushort)(w[i] >> 16);
      }
    }
    asm volatile("s_waitcnt lgkmcnt(0)" ::: "memory");
    __builtin_amdgcn_sched_barrier(0);
    bf16x8 vf[4];
#pragma unroll
    for (int dq = 0; dq < 4; ++dq)
      vf[dq] = *(const bf16x8*)(vt + (dq * 16 + ql) * 40 + lg * 8);
    asm volatile("s_waitcnt lgkmcnt(0)" ::: "memory");
    __builtin_amdgcn_sched_barrier(0);
#pragma unroll
    for (int qt = 0; qt < 2; ++qt) {
      union { uint u[4]; bf16x8 v; } pf;
      pf.u[0] = pw[qt][0]; pf.u[1] = pw[qt][1]; pf.u[2] = pw[qt][2]; pf.u[3] = pw[qt][3];
#pragma unroll
      for (int dq = 0; dq < 4; ++dq)
        oacc[qt][dq] = __builtin_amdgcn_mfma_f32_16x16x32_bf16(vf[dq], pf.v, oacc[qt][dq], 0, 0, 0);
    }
  }

#pragma unroll
  for (int qt = 0; qt < 2; ++qt) {
    float l = lsum[qt];
    l += __shfl_xor(l, 16);
    l += __shfl_xor(l, 32);
    float inv = 1.f / l;
    int qi = q0 + qt * 16 + ql;
    if (qi < n) {
      int p = start + qi;  // sorted space, contiguous
      ushort* op = obuf + (size_t)((bh >> 3) * Sc + p) * Ec + (bh & 7) * HDc + lg * 4;
#pragma unroll
      for (int dq = 0; dq < 4; ++dq) {
        uint w0 = cvtpk(oacc[qt][dq][0] * inv, oacc[qt][dq][1] * inv);
        uint w1 = cvtpk(oacc[qt][dq][2] * inv, oacc[qt][dq][3] * inv);
        uint2 wv = {w0, w1};
        *(uint2*)(op + dq * 16) = wv;
      }
    }
  }
}

extern "C" void kernel_launch(void* const* d_in, const int* in_sizes, int n_in,
                              void* d_out, int out_size, void* d_ws, size_t ws_size,
                              hipStream_t stream) {
  const float* x  = (const float*)d_in[0];
  const float* Wq = (const float*)d_in[1];
  const float* bq = (const float*)d_in[2];
  const float* Wk = (const float*)d_in[3];
  const float* bk = (const float*)d_in[4];
  const float* Wv = (const float*)d_in[5];
  const float* bv = (const float*)d_in[6];
  const float* Wo = (const float*)d_in[7];
  const float* bo = (const float*)d_in[8];
  const int* ids  = (const int*)d_in[9];
  float* out = (float*)d_out;

  char* ws = (char*)d_ws;
  ushort* xb   = (ushort*)(ws);
  ushort* Wcat = (ushort*)(ws + 16777216);
  ushort* Wob  = (ushort*)(ws + 18350080);
  ushort* qkv  = (ushort*)(ws + 18874368);
  ushort* obuf = (ushort*)(ws + 69206016);
  int* perm    = (int*)(ws + 85983232);
  int* gstart  = perm + Sc;
  int* gsz     = gstart + NI;
  int* items   = gsz + NI;
  int* nitems  = items + MAXITEMS;

  prep2_kernel<<<dim3(1 + 1024 + Mtot * Ec / 4 / 256), dim3(256), 0, stream>>>(
      ids, perm, gstart, gsz, items, nitems, Wq, Wk, Wv, Wo, Wcat, Wob, x, xb);
  gemm_qkv128<<<dim3(Mtot / 128 * 12), dim3(256), 0, stream>>>(xb, Wcat, bq, bk, bv, perm, qkv);
  attn5_kernel<<<dim3(MAXITEMS, Bc * Hc), dim3(64), 0, stream>>>(qkv, gstart, gsz, items,
                                                                 nitems, obuf);
  gemm_out128<<<dim3(Mtot / 128 * 4), dim3(256), 0, stream>>>(obuf, Wob, bo, perm, out);
}